// Round 3
// baseline (38634.131 us; speedup 1.0000x reference)
//
#include <hip/hip_runtime.h>
#include <hip/hip_bf16.h>

using bf16 = __hip_bfloat16;

#define EDGES 25000
#define NNODES 5000

__device__ __forceinline__ float sigmf(float x) { return 1.0f / (1.0f + expf(-x)); }

// dtype-flexible load: bf==true -> bf16 elements, else f32 elements
__device__ __forceinline__ float LD(const void* p, size_t i, bool bf) {
    float r;
    if (bf) r = __bfloat162float(((const bf16*)p)[i]);
    else    r = ((const float*)p)[i];
    return r;
}

// monotone float<->uint encoding for atomicMax on floats (incl. negatives)
__device__ __forceinline__ unsigned encF(float f) {
    unsigned b = __float_as_uint(f);
    return (b & 0x80000000u) ? ~b : (b | 0x80000000u);
}
__device__ __forceinline__ float decF(unsigned e) {
    unsigned b = (e & 0x80000000u) ? (e ^ 0x80000000u) : ~e;
    return __uint_as_float(b);
}
#define ENC_NEGINF 0x007FFFFFu  // encF(-inf)

// ---------------- dtype detector ----------------
// edge_distances ~ U[0,1). Interpreted as bf16: if data is really f32, odd
// elements are random mantissa halves -> out of [0,1] with certainty over 256.
__global__ void k_detect(const void* edge_dist, int* flag) {
    if (threadIdx.x == 0 && blockIdx.x == 0) {
        const bf16* p = (const bf16*)edge_dist;
        int ok = 1;
        for (int i = 0; i < 256; i++) {
            float v = __bfloat162float(p[i]);
            if (!(v >= 0.0f && v <= 1.0f)) { ok = 0; break; }
        }
        *flag = ok;
    }
}

// ---------------- fill ----------------
__global__ void k_fill(float* accb, float* nden, unsigned* nmax) {
    int tid = blockIdx.x * 256 + threadIdx.x;
    if (tid < NNODES * 1600) accb[tid] = 0.0f;
    if (tid < NNODES * 8) { nden[tid] = 0.0f; nmax[tid] = ENC_NEGINF; }
}

// ---------------- alpha prepass: logits + seg-max ----------------
__global__ __launch_bounds__(256) void k_alpha(
    const void* __restrict__ node_feats, const void* __restrict__ edge_dist,
    const void* __restrict__ wigner, const void* __restrict__ emb_s,
    const void* __restrict__ emb_r,
    const void* __restrict__ rw1, const void* __restrict__ rb1,
    const void* __restrict__ rl1s, const void* __restrict__ rl1b,
    const void* __restrict__ rw2, const void* __restrict__ rb2,
    const void* __restrict__ rl2s, const void* __restrict__ rl2b,
    const void* __restrict__ rw3, const void* __restrict__ rb3,
    const void* __restrict__ c1w0, const void* __restrict__ c1b0,
    const void* __restrict__ an_s, const void* __restrict__ an_b,
    const void* __restrict__ adot,
    const int* __restrict__ species, const int* __restrict__ senders,
    const int* __restrict__ receivers, const int* __restrict__ dtf,
    float* __restrict__ alpha_out, unsigned* __restrict__ nmax)
{
    __shared__ float X[3200];
    __shared__ float wg5[125];
    __shared__ float x0[640];
    __shared__ float extraA[256];
    __shared__ float xe[192];
    __shared__ float t1[64], h1[64], t2[64], h2[64];
    __shared__ float rad0[640];

    const bool bf = (*dtf != 0);
    const int e = blockIdx.x, t = threadIdx.x;
    const int snd = senders[e], rcv = receivers[e];

    for (int i = t; i < 192; i += 256) {
        float v;
        if (i < 64)       v = LD(edge_dist, (size_t)e * 64 + i, bf);
        else if (i < 128) v = LD(emb_s, (size_t)species[snd] * 64 + (i - 64), bf);
        else              v = LD(emb_r, (size_t)species[rcv] * 64 + (i - 128), bf);
        xe[i] = v;
    }
    for (int i = t; i < 3200; i += 256) {
        int k = i >> 7, c = i & 127;
        X[i] = (c < 64) ? LD(node_feats, (size_t)snd * 1600 + k * 64 + c, bf)
                        : LD(node_feats, (size_t)rcv * 1600 + k * 64 + (c - 64), bf);
    }
    for (int i = t; i < 125; i += 256) wg5[i] = LD(wigner, (size_t)e * 475 + i, bf);
    __syncthreads();

    if (t < 64) {
        float acc = LD(rb1, t, bf);
        for (int k = 0; k < 192; k++) acc += xe[k] * LD(rw1, k * 64 + t, bf);
        t1[t] = acc;
    }
    __syncthreads();
    if (t < 64) {
        float mu = 0.0f;
        for (int k = 0; k < 64; k++) mu += t1[k];
        mu *= (1.0f / 64.0f);
        float var = 0.0f;
        for (int k = 0; k < 64; k++) { float d = t1[k] - mu; var += d * d; }
        float xn = (t1[t] - mu) * rsqrtf(var * (1.0f / 64.0f) + 1e-6f) * LD(rl1s, t, bf) + LD(rl1b, t, bf);
        h1[t] = xn * sigmf(xn);
    }
    __syncthreads();
    if (t < 64) {
        float acc = LD(rb2, t, bf);
        for (int k = 0; k < 64; k++) acc += h1[k] * LD(rw2, k * 64 + t, bf);
        t2[t] = acc;
    }
    __syncthreads();
    if (t < 64) {
        float mu = 0.0f;
        for (int k = 0; k < 64; k++) mu += t2[k];
        mu *= (1.0f / 64.0f);
        float var = 0.0f;
        for (int k = 0; k < 64; k++) { float d = t2[k] - mu; var += d * d; }
        float xn = (t2[t] - mu) * rsqrtf(var * (1.0f / 64.0f) + 1e-6f) * LD(rl2s, t, bf) + LD(rl2b, t, bf);
        h2[t] = xn * sigmf(xn);
    }
    __syncthreads();
    for (int o = t; o < 640; o += 256) {
        float acc = LD(rb3, o, bf);
        for (int k = 0; k < 64; k++) acc += h2[k] * LD(rw3, k * 1536 + o, bf);
        rad0[o] = acc;
    }
    __syncthreads();
    for (int i = t; i < 640; i += 256) {
        int m = i >> 7, c = i & 127;
        float acc = 0.0f;
        #pragma unroll
        for (int k = 0; k < 25; k++) acc += wg5[m * 25 + k] * X[(k << 7) + c];
        x0[i] = acc * rad0[i];
    }
    __syncthreads();
    // alpha columns of y0: cols [320, 576)
    for (int j = t; j < 256; j += 256) {
        float acc = LD(c1b0, 320 + j, bf);
        for (int i = 0; i < 640; i++) acc += x0[i] * LD(c1w0, (size_t)i * 640 + 320 + j, bf);
        extraA[j] = acc;
    }
    __syncthreads();
    if (t < 8) {
        int h = t;
        float mu = 0.0f;
        for (int k = 0; k < 32; k++) mu += extraA[h * 32 + k];
        mu *= (1.0f / 32.0f);
        float var = 0.0f;
        for (int k = 0; k < 32; k++) { float d = extraA[h * 32 + k] - mu; var += d * d; }
        float rs = rsqrtf(var * (1.0f / 32.0f) + 1e-6f);
        float logit = 0.0f;
        for (int k = 0; k < 32; k++) {
            float xn = (extraA[h * 32 + k] - mu) * rs * LD(an_s, k, bf) + LD(an_b, k, bf);
            float slr = 0.6f * xn + 0.4f * xn * (2.0f * sigmf(xn) - 1.0f);
            logit += slr * LD(adot, h * 32 + k, bf);
        }
        alpha_out[e * 8 + h] = logit;
        atomicMax(&nmax[rcv * 8 + h], encF(logit));
    }
}

// ---------------- exp + denom ----------------
__global__ void k_exp(const int* __restrict__ receivers, const unsigned* __restrict__ nmax,
                      float* __restrict__ alpha, float* __restrict__ nden) {
    int tid = blockIdx.x * 256 + threadIdx.x;
    if (tid >= EDGES * 8) return;
    int e = tid >> 3, h = tid & 7;
    int r = receivers[e];
    float m = decF(nmax[r * 8 + h]);
    float ex = expf(alpha[tid] - m);
    alpha[tid] = ex;
    atomicAdd(&nden[r * 8 + h], ex);
}

// ---------------- mega2: full pipeline, fused through projection ----------------
// LDS (floats): [0,1536) rad/feats | [1536,3968) ef1 | [3968,5184) ef2 |
// [5184,5248) gat | [5248,5312) aL | [5312,11712) scr | [11712,14144) ef3 |
// [14144,14619) wv
__global__ __launch_bounds__(256) void k_mega2(
    const void* __restrict__ node_feats, const void* __restrict__ edge_dist,
    const void* __restrict__ wigner, const void* __restrict__ wigner_inv,
    const void* __restrict__ to_grid, const void* __restrict__ from_grid,
    const void* __restrict__ emb_s, const void* __restrict__ emb_r,
    const void* __restrict__ rw1, const void* __restrict__ rb1,
    const void* __restrict__ rl1s, const void* __restrict__ rl1b,
    const void* __restrict__ rw2, const void* __restrict__ rb2,
    const void* __restrict__ rl2s, const void* __restrict__ rl2b,
    const void* __restrict__ rw3, const void* __restrict__ rb3,
    const void* __restrict__ c1w0, const void* __restrict__ c1b0,
    const void* __restrict__ c1w1, const void* __restrict__ c1w2,
    const void* __restrict__ c2w0, const void* __restrict__ c2b0,
    const void* __restrict__ c2w1, const void* __restrict__ c2w2,
    const void* __restrict__ proj_w,
    const int* __restrict__ species, const int* __restrict__ senders,
    const int* __restrict__ receivers, const int* __restrict__ dtf,
    const float* __restrict__ alpha, const float* __restrict__ nden,
    float* __restrict__ accb)
{
    __shared__ float sm[14619];
    float* rad  = sm;
    float* ef1  = sm + 1536;
    float* ef2  = sm + 3968;
    float* gat  = sm + 5184;
    float* aL   = sm + 5248;
    float* scr  = sm + 5312;
    float* ef3  = sm + 11712;
    float* wv   = sm + 14144;

    const bool bf = (*dtf != 0);
    const int e = blockIdx.x, t = threadIdx.x;
    const int snd = senders[e], rcv = receivers[e];

    // ---- P1: radial MLP ----
    float* xe = scr;
    float* t1 = scr + 192;
    float* h1 = scr + 256;
    float* t2 = scr + 320;
    float* h2 = scr + 384;
    for (int i = t; i < 192; i += 256) {
        float v;
        if (i < 64)       v = LD(edge_dist, (size_t)e * 64 + i, bf);
        else if (i < 128) v = LD(emb_s, (size_t)species[snd] * 64 + (i - 64), bf);
        else              v = LD(emb_r, (size_t)species[rcv] * 64 + (i - 128), bf);
        xe[i] = v;
    }
    __syncthreads();
    if (t < 64) {
        float acc = LD(rb1, t, bf);
        for (int k = 0; k < 192; k++) acc += xe[k] * LD(rw1, k * 64 + t, bf);
        t1[t] = acc;
    }
    __syncthreads();
    if (t < 64) {
        float mu = 0.0f;
        for (int k = 0; k < 64; k++) mu += t1[k];
        mu *= (1.0f / 64.0f);
        float var = 0.0f;
        for (int k = 0; k < 64; k++) { float d = t1[k] - mu; var += d * d; }
        float xn = (t1[t] - mu) * rsqrtf(var * (1.0f / 64.0f) + 1e-6f) * LD(rl1s, t, bf) + LD(rl1b, t, bf);
        h1[t] = xn * sigmf(xn);
    }
    __syncthreads();
    if (t < 64) {
        float acc = LD(rb2, t, bf);
        for (int k = 0; k < 64; k++) acc += h1[k] * LD(rw2, k * 64 + t, bf);
        t2[t] = acc;
    }
    __syncthreads();
    if (t < 64) {
        float mu = 0.0f;
        for (int k = 0; k < 64; k++) mu += t2[k];
        mu *= (1.0f / 64.0f);
        float var = 0.0f;
        for (int k = 0; k < 64; k++) { float d = t2[k] - mu; var += d * d; }
        float xn = (t2[t] - mu) * rsqrtf(var * (1.0f / 64.0f) + 1e-6f) * LD(rl2s, t, bf) + LD(rl2b, t, bf);
        h2[t] = xn * sigmf(xn);
    }
    __syncthreads();
    for (int o = t; o < 1536; o += 256) {
        float acc = LD(rb3, o, bf);
        for (int k = 0; k < 64; k++) acc += h2[k] * LD(rw3, k * 1536 + o, bf);
        rad[o] = acc;
    }
    __syncthreads();

    // ---- P2: gather + wigner rotate + rad scale ----
    float* X  = scr;
    float* wg = scr + 3200;
    for (int i = t; i < 3200; i += 256) {
        int k = i >> 7, c = i & 127;
        X[i] = (c < 64) ? LD(node_feats, (size_t)snd * 1600 + k * 64 + c, bf)
                        : LD(node_feats, (size_t)rcv * 1600 + k * 64 + (c - 64), bf);
    }
    for (int i = t; i < 475; i += 256) wg[i] = LD(wigner, (size_t)e * 475 + i, bf);
    __syncthreads();
    for (int i = t; i < 2432; i += 256) {
        int m = i >> 7, c = i & 127;
        float acc = 0.0f;
        #pragma unroll
        for (int k = 0; k < 25; k++) acc += wg[m * 25 + k] * X[(k << 7) + c];
        ef1[i] = acc;
    }
    __syncthreads();
    for (int i = t; i < 2432; i += 256) {
        int m = i >> 7, c = i & 127;
        int ri;
        if (m < 5)       ri = i;
        else if (m < 13) ri = 640 + (((m - 5) & 3) << 7) + c;
        else             ri = 1152 + ((m - 13) % 3) * 128 + c;
        ef1[i] *= rad[ri];
    }
    __syncthreads();

    // ---- P3: conv1 ----
    float* y0 = scr;
    float* y1 = scr + 1024;
    for (int jj = t; jj < 384; jj += 256) {
        int j = (jj < 320) ? jj : (jj + 256);
        float acc = LD(c1b0, j, bf);
        for (int i = 0; i < 640; i++) acc += ef1[i] * LD(c1w0, (size_t)i * 640 + j, bf);
        if (jj < 320) ef2[jj] = acc; else gat[jj - 320] = acc;
    }
    for (int j = t; j < 512; j += 256) {
        float a0 = 0.0f, a1 = 0.0f;
        for (int i = 0; i < 512; i++) {
            float w = LD(c1w1, (size_t)i * 512 + j, bf);
            a0 += ef1[640 + i] * w; a1 += ef1[1152 + i] * w;
        }
        y0[j] = a0; y1[j] = a1;
    }
    __syncthreads();
    {
        int j = t;
        ef2[320 + j] = y0[j] - y1[256 + j];
        ef2[576 + j] = y1[j] + y0[256 + j];
    }
    __syncthreads();
    for (int j = t; j < 384; j += 256) {
        float a0 = 0.0f, a1 = 0.0f;
        for (int i = 0; i < 384; i++) {
            float w = LD(c1w2, (size_t)i * 384 + j, bf);
            a0 += ef1[1664 + i] * w; a1 += ef1[2048 + i] * w;
        }
        y0[j] = a0; y1[j] = a1;
    }
    __syncthreads();
    for (int j = t; j < 192; j += 256) {
        ef2[832 + j]  = y0[j] - y1[192 + j];
        ef2[1024 + j] = y1[j] + y0[192 + j];
    }
    __syncthreads();

    // ---- P4: grid nonlinearity ----
    float* g = scr;
    for (int i = t; i < 6400; i += 256) {
        int gi = i >> 6, c = i & 63;
        float acc = 0.0f;
        #pragma unroll
        for (int m = 0; m < 19; m++) acc += LD(to_grid, gi * 19 + m, bf) * ef2[(m << 6) + c];
        g[i] = acc * sigmf(acc);
    }
    __syncthreads();
    float* feats = rad;
    for (int i = t; i < 1216; i += 256) {
        int m = i >> 6, c = i & 63;
        float acc = 0.0f;
        for (int gi = 0; gi < 100; gi++) acc += LD(from_grid, gi * 19 + m, bf) * g[(gi << 6) + c];
        feats[i] = acc;
    }
    __syncthreads();
    if (t < 64) { float x = gat[t]; feats[t] = x * sigmf(x); }
    __syncthreads();

    // ---- P5: conv2 -> ef3 (LDS) ----
    for (int j = t; j < 640; j += 256) {
        float acc = LD(c2b0, j, bf);
        for (int i = 0; i < 320; i++) acc += feats[i] * LD(c2w0, (size_t)i * 640 + j, bf);
        ef3[j] = acc;
    }
    for (int j = t; j < 1024; j += 256) {
        float a0 = 0.0f, a1 = 0.0f;
        for (int i = 0; i < 256; i++) {
            float w = LD(c2w1, (size_t)i * 1024 + j, bf);
            a0 += feats[320 + i] * w; a1 += feats[576 + i] * w;
        }
        y0[j] = a0; y1[j] = a1;
    }
    __syncthreads();
    for (int j = t; j < 512; j += 256) {
        ef3[640 + j]  = y0[j] - y1[512 + j];
        ef3[1152 + j] = y1[j] + y0[512 + j];
    }
    __syncthreads();
    for (int j = t; j < 768; j += 256) {
        float a0 = 0.0f, a1 = 0.0f;
        for (int i = 0; i < 192; i++) {
            float w = LD(c2w2, (size_t)i * 768 + j, bf);
            a0 += feats[832 + i] * w; a1 += feats[1024 + i] * w;
        }
        y0[j] = a0; y1[j] = a1;
    }
    __syncthreads();
    for (int j = t; j < 384; j += 256) {
        ef3[1664 + j] = __fadd_rn(y0[j], -y1[384 + j]);
        ef3[2048 + j] = __fadd_rn(y1[j],  y0[384 + j]);
    }

    // ---- P7: alpha + wigner_inv rotate + fused projection + scatter ----
    for (int i = t; i < 475; i += 256) wv[i] = LD(wigner_inv, (size_t)e * 475 + i, bf);
    if (t < 8) aL[t] = alpha[e * 8 + t] / (nden[rcv * 8 + t] + 1e-16f);
    __syncthreads();
    float* eo = scr;  // 25 x 128
    for (int i = t; i < 3200; i += 256) {
        int k = i >> 7, c = i & 127;
        float acc = 0.0f;
        #pragma unroll
        for (int m = 0; m < 19; m++) acc += wv[k * 19 + m] * ef3[(m << 7) + c];
        eo[i] = acc * aL[c >> 4];
    }
    __syncthreads();
    const int ls25[25] = {0,1,1,1,2,2,2,2,2,3,3,3,3,3,3,3,4,4,4,4,4,4,4,4,4};
    for (int i = t; i < 1600; i += 256) {
        int k = i >> 6, o = i & 63;
        size_t base = (size_t)ls25[k] * 8192 + o;
        float acc = 0.0f;
        for (int c = 0; c < 128; c++) acc += eo[(k << 7) + c] * LD(proj_w, base + (size_t)c * 64, bf);
        atomicAdd(&accb[(size_t)rcv * 1600 + i], acc);
    }
}

// ---------------- bias + convert ----------------
__global__ void k_out(const float* __restrict__ accb, const void* __restrict__ proj_b,
                      void* __restrict__ out, const int* __restrict__ dtf) {
    int i = blockIdx.x * 256 + threadIdx.x;
    if (i >= NNODES * 1600) return;
    const bool bf = (*dtf != 0);
    int r = i % 1600;
    int m = r >> 6, o = r & 63;
    float v = accb[i] + ((m == 0) ? LD(proj_b, o, bf) : 0.0f);
    if (bf) ((bf16*)out)[i] = __float2bfloat16(v);
    else    ((float*)out)[i] = v;
}

extern "C" void kernel_launch(void* const* d_in, const int* in_sizes, int n_in,
                              void* d_out, int out_size, void* d_ws, size_t ws_size,
                              hipStream_t stream) {
    const void* node_feats = d_in[0];
    const void* edge_dist  = d_in[1];
    const void* wigner     = d_in[2];
    const void* wigner_inv = d_in[3];
    const void* to_grid    = d_in[4];
    const void* from_grid  = d_in[5];
    const void* emb_s      = d_in[6];
    const void* emb_r      = d_in[7];
    const void* rw1  = d_in[8];
    const void* rb1  = d_in[9];
    const void* rl1s = d_in[10];
    const void* rl1b = d_in[11];
    const void* rw2  = d_in[12];
    const void* rb2  = d_in[13];
    const void* rl2s = d_in[14];
    const void* rl2b = d_in[15];
    const void* rw3  = d_in[16];
    const void* rb3  = d_in[17];
    const void* c1w0 = d_in[18];
    const void* c1b0 = d_in[19];
    const void* c1w1 = d_in[20];
    const void* c1w2 = d_in[21];
    const void* c2w0 = d_in[22];
    const void* c2b0 = d_in[23];
    const void* c2w1 = d_in[24];
    const void* c2w2 = d_in[25];
    const void* an_s = d_in[26];
    const void* an_b = d_in[27];
    const void* adot = d_in[28];
    const void* proj_w = d_in[29];
    const void* proj_b = d_in[30];
    const int* species   = (const int*)d_in[31];
    const int* senders   = (const int*)d_in[32];
    const int* receivers = (const int*)d_in[33];

    char* ws = (char*)d_ws;
    float*    accb  = (float*)ws;                   // 5000*1600*4 = 32,000,000 B
    float*    alpha = (float*)(ws + 32000000);      // 800,000 B
    unsigned* nmax  = (unsigned*)(ws + 32800000);   // 160,000 B
    float*    nden  = (float*)(ws + 32960000);      // 160,000 B
    int*      dtf   = (int*)(ws + 33120000);        // 4 B   (total ~33.12 MB)

    k_detect<<<1, 64, 0, stream>>>(edge_dist, dtf);
    k_fill<<<(NNODES * 1600 + 255) / 256, 256, 0, stream>>>(accb, nden, nmax);
    k_alpha<<<EDGES, 256, 0, stream>>>(
        node_feats, edge_dist, wigner, emb_s, emb_r,
        rw1, rb1, rl1s, rl1b, rw2, rb2, rl2s, rl2b, rw3, rb3,
        c1w0, c1b0, an_s, an_b, adot, species, senders, receivers, dtf,
        alpha, nmax);
    k_exp<<<(EDGES * 8 + 255) / 256, 256, 0, stream>>>(receivers, nmax, alpha, nden);
    k_mega2<<<EDGES, 256, 0, stream>>>(
        node_feats, edge_dist, wigner, wigner_inv, to_grid, from_grid, emb_s, emb_r,
        rw1, rb1, rl1s, rl1b, rw2, rb2, rl2s, rl2b, rw3, rb3,
        c1w0, c1b0, c1w1, c1w2, c2w0, c2b0, c2w1, c2w2, proj_w,
        species, senders, receivers, dtf, alpha, nden, accb);
    k_out<<<(NNODES * 1600 + 255) / 256, 256, 0, stream>>>(accb, proj_b, d_out, dtf);
}

// Round 4
// 7965.694 us; speedup vs baseline: 4.8501x; 4.8501x over previous
//
#include <hip/hip_runtime.h>
#include <hip/hip_bf16.h>

using bf16 = __hip_bfloat16;

#define EDGES 25000
#define NNODES 5000

__device__ __forceinline__ float sigmf(float x) { return 1.0f / (1.0f + expf(-x)); }

template<bool BF>
__device__ __forceinline__ float LD1(const void* p, size_t i) {
    if (BF) return __bfloat162float(((const bf16*)p)[i]);
    else    return ((const float*)p)[i];
}

template<bool BF>
__device__ __forceinline__ float4 LD4(const void* p, size_t i) {
    if (BF) {
        ushort4 u = *reinterpret_cast<const ushort4*>((const bf16*)p + i);
        float4 r;
        r.x = __uint_as_float((unsigned)u.x << 16);
        r.y = __uint_as_float((unsigned)u.y << 16);
        r.z = __uint_as_float((unsigned)u.z << 16);
        r.w = __uint_as_float((unsigned)u.w << 16);
        return r;
    } else {
        return *reinterpret_cast<const float4*>((const float*)p + i);
    }
}

__device__ __forceinline__ void fma4(float4& a, float s, const float4& w) {
    a.x += s * w.x; a.y += s * w.y; a.z += s * w.z; a.w += s * w.w;
}

// monotone float<->uint encoding for atomicMax on floats
__device__ __forceinline__ unsigned encF(float f) {
    unsigned b = __float_as_uint(f);
    return (b & 0x80000000u) ? ~b : (b | 0x80000000u);
}
__device__ __forceinline__ float decF(unsigned e) {
    unsigned b = (e & 0x80000000u) ? (e ^ 0x80000000u) : ~e;
    return __uint_as_float(b);
}
#define ENC_NEGINF 0x007FFFFFu

// ---------------- dtype detector ----------------
__global__ void k_detect(const void* edge_dist, int* flag) {
    if (threadIdx.x == 0 && blockIdx.x == 0) {
        const bf16* p = (const bf16*)edge_dist;
        int ok = 1;
        for (int i = 0; i < 256; i++) {
            float v = __bfloat162float(p[i]);
            if (!(v >= 0.0f && v <= 1.0f)) { ok = 0; break; }
        }
        *flag = ok;
    }
}

// ---------------- fill ----------------
__global__ void k_fill(float* accb, float* nden, unsigned* nmax) {
    int tid = blockIdx.x * 256 + threadIdx.x;
    if (tid < NNODES * 1600) accb[tid] = 0.0f;
    if (tid < NNODES * 8) { nden[tid] = 0.0f; nmax[tid] = ENC_NEGINF; }
}

// ---------------- alpha prepass ----------------
// sm layout (floats): X@0(3200) wg5@3200(128) x0@3328(640) extraA@3968(256)
// xe@4224(192) t1@4416 h1@4480 t2@4544 h2@4608 rad0@4672(640) -> 5312
template<bool BF>
__global__ __launch_bounds__(256) void k_alpha(
    const void* __restrict__ node_feats, const void* __restrict__ edge_dist,
    const void* __restrict__ wigner, const void* __restrict__ emb_s,
    const void* __restrict__ emb_r,
    const void* __restrict__ rw1, const void* __restrict__ rb1,
    const void* __restrict__ rl1s, const void* __restrict__ rl1b,
    const void* __restrict__ rw2, const void* __restrict__ rb2,
    const void* __restrict__ rl2s, const void* __restrict__ rl2b,
    const void* __restrict__ rw3, const void* __restrict__ rb3,
    const void* __restrict__ c1w0, const void* __restrict__ c1b0,
    const void* __restrict__ an_s, const void* __restrict__ an_b,
    const void* __restrict__ adot,
    const int* __restrict__ species, const int* __restrict__ senders,
    const int* __restrict__ receivers, const int* __restrict__ dtf,
    float* __restrict__ alpha_out, unsigned* __restrict__ nmax)
{
    if ((*dtf != 0) != BF) return;
    __shared__ __align__(16) float sm[5312];
    float* X = sm;
    float* wg5 = sm + 3200;
    float* x0 = sm + 3328;
    float* extraA = sm + 3968;
    float* xe = sm + 4224;
    float* t1 = sm + 4416;
    float* h1 = sm + 4480;
    float* t2 = sm + 4544;
    float* h2 = sm + 4608;
    float* rad0 = sm + 4672;

    const int e = blockIdx.x, t = threadIdx.x;
    const int snd = senders[e], rcv = receivers[e];

    for (int i = t; i < 192; i += 256) {
        float v;
        if (i < 64)       v = LD1<BF>(edge_dist, (size_t)e * 64 + i);
        else if (i < 128) v = LD1<BF>(emb_s, (size_t)species[snd] * 64 + (i - 64));
        else              v = LD1<BF>(emb_r, (size_t)species[rcv] * 64 + (i - 128));
        xe[i] = v;
    }
    for (int q = t; q < 800; q += 256) {
        int k = q >> 5, c0 = (q & 31) * 4;
        float4 v = (c0 < 64) ? LD4<BF>(node_feats, (size_t)snd * 1600 + k * 64 + c0)
                             : LD4<BF>(node_feats, (size_t)rcv * 1600 + k * 64 + (c0 - 64));
        *(float4*)&X[q * 4] = v;
    }
    for (int i = t; i < 125; i += 256) wg5[i] = LD1<BF>(wigner, (size_t)e * 475 + i);
    __syncthreads();

    if (t < 64) {
        float acc = LD1<BF>(rb1, t);
        for (int k = 0; k < 192; k++) acc += xe[k] * LD1<BF>(rw1, k * 64 + t);
        t1[t] = acc;
    }
    __syncthreads();
    if (t < 64) {
        float mu = 0.0f;
        for (int k = 0; k < 64; k++) mu += t1[k];
        mu *= (1.0f / 64.0f);
        float var = 0.0f;
        for (int k = 0; k < 64; k++) { float d = t1[k] - mu; var += d * d; }
        float xn = (t1[t] - mu) * rsqrtf(var * (1.0f / 64.0f) + 1e-6f) * LD1<BF>(rl1s, t) + LD1<BF>(rl1b, t);
        h1[t] = xn * sigmf(xn);
    }
    __syncthreads();
    if (t < 64) {
        float acc = LD1<BF>(rb2, t);
        for (int k = 0; k < 64; k++) acc += h1[k] * LD1<BF>(rw2, k * 64 + t);
        t2[t] = acc;
    }
    __syncthreads();
    if (t < 64) {
        float mu = 0.0f;
        for (int k = 0; k < 64; k++) mu += t2[k];
        mu *= (1.0f / 64.0f);
        float var = 0.0f;
        for (int k = 0; k < 64; k++) { float d = t2[k] - mu; var += d * d; }
        float xn = (t2[t] - mu) * rsqrtf(var * (1.0f / 64.0f) + 1e-6f) * LD1<BF>(rl2s, t) + LD1<BF>(rl2b, t);
        h2[t] = xn * sigmf(xn);
    }
    __syncthreads();
    if (t < 160) {  // rad0: first 640 outputs of rad
        int j0 = t * 4;
        float4 acc = LD4<BF>(rb3, j0);
        for (int k = 0; k < 64; k++) fma4(acc, h2[k], LD4<BF>(rw3, (size_t)k * 1536 + j0));
        *(float4*)&rad0[j0] = acc;
    }
    __syncthreads();
    if (t < 160) {  // rotate rows 0..4 + rad scale
        int q = t, m = q >> 5, c0 = (q & 31) * 4;
        float4 acc = {0.f, 0.f, 0.f, 0.f};
        #pragma unroll
        for (int k = 0; k < 25; k++) fma4(acc, wg5[m * 25 + k], *(const float4*)&X[k * 128 + c0]);
        float4 rv = *(const float4*)&rad0[q * 4];
        acc.x *= rv.x; acc.y *= rv.y; acc.z *= rv.z; acc.w *= rv.w;
        *(float4*)&x0[q * 4] = acc;
    }
    __syncthreads();
    if (t < 64) {  // alpha cols [320,576) of conv1-m0
        int j0 = 320 + t * 4;
        float4 acc = LD4<BF>(c1b0, j0);
        for (int i = 0; i < 640; i++) fma4(acc, x0[i], LD4<BF>(c1w0, (size_t)i * 640 + j0));
        *(float4*)&extraA[t * 4] = acc;
    }
    __syncthreads();
    if (t < 8) {
        int h = t;
        float mu = 0.0f;
        for (int k = 0; k < 32; k++) mu += extraA[h * 32 + k];
        mu *= (1.0f / 32.0f);
        float var = 0.0f;
        for (int k = 0; k < 32; k++) { float d = extraA[h * 32 + k] - mu; var += d * d; }
        float rs = rsqrtf(var * (1.0f / 32.0f) + 1e-6f);
        float logit = 0.0f;
        for (int k = 0; k < 32; k++) {
            float xn = (extraA[h * 32 + k] - mu) * rs * LD1<BF>(an_s, k) + LD1<BF>(an_b, k);
            float slr = 0.6f * xn + 0.4f * xn * (2.0f * sigmf(xn) - 1.0f);
            logit += slr * LD1<BF>(adot, h * 32 + k);
        }
        alpha_out[e * 8 + h] = logit;
        atomicMax(&nmax[rcv * 8 + h], encF(logit));
    }
}

// ---------------- exp + denom ----------------
__global__ void k_exp(const int* __restrict__ receivers, const unsigned* __restrict__ nmax,
                      float* __restrict__ alpha, float* __restrict__ nden) {
    int tid = blockIdx.x * 256 + threadIdx.x;
    if (tid >= EDGES * 8) return;
    int e = tid >> 3, h = tid & 7;
    int r = receivers[e];
    float m = decF(nmax[r * 8 + h]);
    float ex = expf(alpha[tid] - m);
    alpha[tid] = ex;
    atomicAdd(&nden[r * 8 + h], ex);
}

// ---------------- mega2 ----------------
// sm (floats): rad@0(1536) ef1@1536(2432) ef2@3968(1216) gat@5184(64)
// aL@5248(16) scr@5264(3680) ef3@8944(2432) wv@11376(480) -> 11856 = 47424 B
template<bool BF>
__global__ __launch_bounds__(256) void k_mega2(
    const void* __restrict__ node_feats, const void* __restrict__ edge_dist,
    const void* __restrict__ wigner, const void* __restrict__ wigner_inv,
    const void* __restrict__ to_grid, const void* __restrict__ from_grid,
    const void* __restrict__ emb_s, const void* __restrict__ emb_r,
    const void* __restrict__ rw1, const void* __restrict__ rb1,
    const void* __restrict__ rl1s, const void* __restrict__ rl1b,
    const void* __restrict__ rw2, const void* __restrict__ rb2,
    const void* __restrict__ rl2s, const void* __restrict__ rl2b,
    const void* __restrict__ rw3, const void* __restrict__ rb3,
    const void* __restrict__ c1w0, const void* __restrict__ c1b0,
    const void* __restrict__ c1w1, const void* __restrict__ c1w2,
    const void* __restrict__ c2w0, const void* __restrict__ c2b0,
    const void* __restrict__ c2w1, const void* __restrict__ c2w2,
    const void* __restrict__ proj_w,
    const int* __restrict__ species, const int* __restrict__ senders,
    const int* __restrict__ receivers, const int* __restrict__ dtf,
    const float* __restrict__ alpha, const float* __restrict__ nden,
    float* __restrict__ accb)
{
    if ((*dtf != 0) != BF) return;
    __shared__ __align__(16) float sm[11856];
    float* rad = sm;
    float* ef1 = sm + 1536;
    float* ef2 = sm + 3968;
    float* gat = sm + 5184;
    float* aL  = sm + 5248;
    float* scr = sm + 5264;
    float* ef3 = sm + 8944;
    float* wv  = sm + 11376;

    const int e = blockIdx.x, t = threadIdx.x;
    const int snd = senders[e], rcv = receivers[e];

    // ---- P1: radial MLP ----
    float* xe = scr;
    float* t1 = scr + 192;
    float* h1 = scr + 256;
    float* t2 = scr + 320;
    float* h2 = scr + 384;
    for (int i = t; i < 192; i += 256) {
        float v;
        if (i < 64)       v = LD1<BF>(edge_dist, (size_t)e * 64 + i);
        else if (i < 128) v = LD1<BF>(emb_s, (size_t)species[snd] * 64 + (i - 64));
        else              v = LD1<BF>(emb_r, (size_t)species[rcv] * 64 + (i - 128));
        xe[i] = v;
    }
    __syncthreads();
    if (t < 64) {
        float acc = LD1<BF>(rb1, t);
        for (int k = 0; k < 192; k++) acc += xe[k] * LD1<BF>(rw1, k * 64 + t);
        t1[t] = acc;
    }
    __syncthreads();
    if (t < 64) {
        float mu = 0.0f;
        for (int k = 0; k < 64; k++) mu += t1[k];
        mu *= (1.0f / 64.0f);
        float var = 0.0f;
        for (int k = 0; k < 64; k++) { float d = t1[k] - mu; var += d * d; }
        float xn = (t1[t] - mu) * rsqrtf(var * (1.0f / 64.0f) + 1e-6f) * LD1<BF>(rl1s, t) + LD1<BF>(rl1b, t);
        h1[t] = xn * sigmf(xn);
    }
    __syncthreads();
    if (t < 64) {
        float acc = LD1<BF>(rb2, t);
        for (int k = 0; k < 64; k++) acc += h1[k] * LD1<BF>(rw2, k * 64 + t);
        t2[t] = acc;
    }
    __syncthreads();
    if (t < 64) {
        float mu = 0.0f;
        for (int k = 0; k < 64; k++) mu += t2[k];
        mu *= (1.0f / 64.0f);
        float var = 0.0f;
        for (int k = 0; k < 64; k++) { float d = t2[k] - mu; var += d * d; }
        float xn = (t2[t] - mu) * rsqrtf(var * (1.0f / 64.0f) + 1e-6f) * LD1<BF>(rl2s, t) + LD1<BF>(rl2b, t);
        h2[t] = xn * sigmf(xn);
    }
    __syncthreads();
    for (int q = t; q < 384; q += 256) {  // rad = h2@W3 + b3 (1536 outs)
        int j0 = q * 4;
        float4 acc = LD4<BF>(rb3, j0);
        for (int k = 0; k < 64; k++) fma4(acc, h2[k], LD4<BF>(rw3, (size_t)k * 1536 + j0));
        *(float4*)&rad[j0] = acc;
    }
    __syncthreads();

    // ---- P2: gather + wigner rotate + rad scale ----
    float* X  = scr;          // 3200
    float* wg = scr + 3200;   // 475
    for (int q = t; q < 800; q += 256) {
        int k = q >> 5, c0 = (q & 31) * 4;
        float4 v = (c0 < 64) ? LD4<BF>(node_feats, (size_t)snd * 1600 + k * 64 + c0)
                             : LD4<BF>(node_feats, (size_t)rcv * 1600 + k * 64 + (c0 - 64));
        *(float4*)&X[q * 4] = v;
    }
    for (int i = t; i < 475; i += 256) wg[i] = LD1<BF>(wigner, (size_t)e * 475 + i);
    __syncthreads();
    for (int q = t; q < 608; q += 256) {  // 19 x 128 = 2432
        int m = q >> 5, c0 = (q & 31) * 4;
        float4 acc = {0.f, 0.f, 0.f, 0.f};
        #pragma unroll
        for (int k = 0; k < 25; k++) fma4(acc, wg[m * 25 + k], *(const float4*)&X[k * 128 + c0]);
        int ri0;
        if (m < 5)       ri0 = m * 128 + c0;
        else if (m < 13) ri0 = 640 + ((m - 5) & 3) * 128 + c0;
        else             ri0 = 1152 + ((m - 13) % 3) * 128 + c0;
        float4 rv = *(const float4*)&rad[ri0];
        acc.x *= rv.x; acc.y *= rv.y; acc.z *= rv.z; acc.w *= rv.w;
        *(float4*)&ef1[q * 4] = acc;
    }
    __syncthreads();

    // ---- P3: conv1 ----
    float* y0 = scr;
    float* y1 = scr + 1024;
    if (t < 96) {  // m0: cols [0,320) + [576,640)
        int j0 = (t < 80) ? t * 4 : 576 + (t - 80) * 4;
        float4 acc = LD4<BF>(c1b0, j0);
        for (int i = 0; i < 640; i++) fma4(acc, ef1[i], LD4<BF>(c1w0, (size_t)i * 640 + j0));
        if (t < 80) *(float4*)&ef2[t * 4] = acc;
        else        *(float4*)&gat[(t - 80) * 4] = acc;
    }
    if (t >= 128) {  // m1: 512 cols, 2 rows (threads 128..255)
        int j0 = (t - 128) * 4;
        float4 a0 = {0.f,0.f,0.f,0.f}, a1 = {0.f,0.f,0.f,0.f};
        for (int i = 0; i < 512; i++) {
            float4 w = LD4<BF>(c1w1, (size_t)i * 512 + j0);
            fma4(a0, ef1[640 + i], w);
            fma4(a1, ef1[1152 + i], w);
        }
        *(float4*)&y0[j0] = a0;
        *(float4*)&y1[j0] = a1;
    }
    __syncthreads();
    {
        int j = t;
        ef2[320 + j] = y0[j] - y1[256 + j];
        ef2[576 + j] = y1[j] + y0[256 + j];
    }
    __syncthreads();
    if (t < 96) {  // m2: 384 cols, 2 rows
        int j0 = t * 4;
        float4 a0 = {0.f,0.f,0.f,0.f}, a1 = {0.f,0.f,0.f,0.f};
        for (int i = 0; i < 384; i++) {
            float4 w = LD4<BF>(c1w2, (size_t)i * 384 + j0);
            fma4(a0, ef1[1664 + i], w);
            fma4(a1, ef1[2048 + i], w);
        }
        *(float4*)&y0[j0] = a0;
        *(float4*)&y1[j0] = a1;
    }
    __syncthreads();
    for (int j = t; j < 192; j += 256) {
        ef2[832 + j]  = y0[j] - y1[192 + j];
        ef2[1024 + j] = y1[j] + y0[192 + j];
    }
    __syncthreads();

    // ---- P4: grid nonlinearity (2 chunks of 50 grid points) ----
    float* feats = rad;  // rad dead
    float* g = scr;      // 50 x 64 = 3200
    for (int q = t; q < 304; q += 256) *(float4*)&feats[q * 4] = make_float4(0.f, 0.f, 0.f, 0.f);
    for (int ch = 0; ch < 2; ch++) {
        int gbase = ch * 50;
        for (int q = t; q < 800; q += 256) {
            int gi = q >> 4, c0 = (q & 15) * 4;
            float4 acc = {0.f,0.f,0.f,0.f};
            #pragma unroll
            for (int m = 0; m < 19; m++)
                fma4(acc, LD1<BF>(to_grid, (gbase + gi) * 19 + m), *(const float4*)&ef2[m * 64 + c0]);
            acc.x *= sigmf(acc.x); acc.y *= sigmf(acc.y); acc.z *= sigmf(acc.z); acc.w *= sigmf(acc.w);
            *(float4*)&g[q * 4] = acc;
        }
        __syncthreads();
        for (int q = t; q < 304; q += 256) {
            int m = q >> 4, c0 = (q & 15) * 4;
            float4 acc = *(const float4*)&feats[q * 4];
            for (int gi = 0; gi < 50; gi++)
                fma4(acc, LD1<BF>(from_grid, (gbase + gi) * 19 + m), *(const float4*)&g[gi * 64 + c0]);
            *(float4*)&feats[q * 4] = acc;
        }
        __syncthreads();
    }
    if (t < 64) { float x = gat[t]; feats[t] = x * sigmf(x); }
    __syncthreads();

    // ---- P5: conv2 -> ef3 (LDS) ----
    if (t < 160) {  // m0: 640 outs, k=320
        int j0 = t * 4;
        float4 acc = LD4<BF>(c2b0, j0);
        for (int i = 0; i < 320; i++) fma4(acc, feats[i], LD4<BF>(c2w0, (size_t)i * 640 + j0));
        *(float4*)&ef3[j0] = acc;
    }
    {  // m1: 1024 outs, 2 rows, k=256 (all 256 threads)
        int j0 = t * 4;
        float4 a0 = {0.f,0.f,0.f,0.f}, a1 = {0.f,0.f,0.f,0.f};
        for (int i = 0; i < 256; i++) {
            float4 w = LD4<BF>(c2w1, (size_t)i * 1024 + j0);
            fma4(a0, feats[320 + i], w);
            fma4(a1, feats[576 + i], w);
        }
        *(float4*)&y0[j0] = a0;
        *(float4*)&y1[j0] = a1;
    }
    __syncthreads();
    for (int j = t; j < 512; j += 256) {
        ef3[640 + j]  = y0[j] - y1[512 + j];
        ef3[1152 + j] = y1[j] + y0[512 + j];
    }
    __syncthreads();
    if (t < 192) {  // m2: 768 outs, 2 rows, k=192
        int j0 = t * 4;
        float4 a0 = {0.f,0.f,0.f,0.f}, a1 = {0.f,0.f,0.f,0.f};
        for (int i = 0; i < 192; i++) {
            float4 w = LD4<BF>(c2w2, (size_t)i * 768 + j0);
            fma4(a0, feats[832 + i], w);
            fma4(a1, feats[1024 + i], w);
        }
        *(float4*)&y0[j0] = a0;
        *(float4*)&y1[j0] = a1;
    }
    __syncthreads();
    for (int j = t; j < 384; j += 256) {
        ef3[1664 + j] = y0[j] - y1[384 + j];
        ef3[2048 + j] = y1[j] + y0[384 + j];
    }

    // ---- P7: alpha + wigner_inv rotate + fused projection + scatter ----
    for (int i = t; i < 475; i += 256) wv[i] = LD1<BF>(wigner_inv, (size_t)e * 475 + i);
    if (t < 8) aL[t] = alpha[e * 8 + t] / (nden[rcv * 8 + t] + 1e-16f);
    __syncthreads();
    float* eo = scr;  // 25 x 128
    for (int q = t; q < 800; q += 256) {
        int k = q >> 5, c0 = (q & 31) * 4;
        float4 acc = {0.f,0.f,0.f,0.f};
        #pragma unroll
        for (int m = 0; m < 19; m++) fma4(acc, wv[k * 19 + m], *(const float4*)&ef3[m * 128 + c0]);
        float al = aL[c0 >> 4];
        acc.x *= al; acc.y *= al; acc.z *= al; acc.w *= al;
        *(float4*)&eo[q * 4] = acc;
    }
    __syncthreads();
    const int ls25[25] = {0,1,1,1,2,2,2,2,2,3,3,3,3,3,3,3,4,4,4,4,4,4,4,4,4};
    for (int q = t; q < 400; q += 256) {
        int k = q >> 4, o0 = (q & 15) * 4;
        size_t base = (size_t)ls25[k] * 8192 + o0;
        float4 acc = {0.f,0.f,0.f,0.f};
        for (int c = 0; c < 128; c++) fma4(acc, eo[k * 128 + c], LD4<BF>(proj_w, base + (size_t)c * 64));
        float* dst = &accb[(size_t)rcv * 1600 + k * 64 + o0];
        atomicAdd(dst + 0, acc.x);
        atomicAdd(dst + 1, acc.y);
        atomicAdd(dst + 2, acc.z);
        atomicAdd(dst + 3, acc.w);
    }
}

// ---------------- bias + convert ----------------
template<bool BF>
__global__ void k_out(const float* __restrict__ accb, const void* __restrict__ proj_b,
                      void* __restrict__ out, const int* __restrict__ dtf) {
    if ((*dtf != 0) != BF) return;
    int i = blockIdx.x * 256 + threadIdx.x;
    if (i >= NNODES * 1600) return;
    int r = i % 1600;
    int m = r >> 6, o = r & 63;
    float v = accb[i] + ((m == 0) ? LD1<BF>(proj_b, o) : 0.0f);
    if (BF) ((bf16*)out)[i] = __float2bfloat16(v);
    else    ((float*)out)[i] = v;
}

extern "C" void kernel_launch(void* const* d_in, const int* in_sizes, int n_in,
                              void* d_out, int out_size, void* d_ws, size_t ws_size,
                              hipStream_t stream) {
    const void* node_feats = d_in[0];
    const void* edge_dist  = d_in[1];
    const void* wigner     = d_in[2];
    const void* wigner_inv = d_in[3];
    const void* to_grid    = d_in[4];
    const void* from_grid  = d_in[5];
    const void* emb_s      = d_in[6];
    const void* emb_r      = d_in[7];
    const void* rw1  = d_in[8];
    const void* rb1  = d_in[9];
    const void* rl1s = d_in[10];
    const void* rl1b = d_in[11];
    const void* rw2  = d_in[12];
    const void* rb2  = d_in[13];
    const void* rl2s = d_in[14];
    const void* rl2b = d_in[15];
    const void* rw3  = d_in[16];
    const void* rb3  = d_in[17];
    const void* c1w0 = d_in[18];
    const void* c1b0 = d_in[19];
    const void* c1w1 = d_in[20];
    const void* c1w2 = d_in[21];
    const void* c2w0 = d_in[22];
    const void* c2b0 = d_in[23];
    const void* c2w1 = d_in[24];
    const void* c2w2 = d_in[25];
    const void* an_s = d_in[26];
    const void* an_b = d_in[27];
    const void* adot = d_in[28];
    const void* proj_w = d_in[29];
    const void* proj_b = d_in[30];
    const int* species   = (const int*)d_in[31];
    const int* senders   = (const int*)d_in[32];
    const int* receivers = (const int*)d_in[33];

    char* ws = (char*)d_ws;
    float*    accb  = (float*)ws;                   // 32,000,000 B
    float*    alpha = (float*)(ws + 32000000);      // 800,000 B
    unsigned* nmax  = (unsigned*)(ws + 32800000);   // 160,000 B
    float*    nden  = (float*)(ws + 32960000);      // 160,000 B
    int*      dtf   = (int*)(ws + 33120000);        // 4 B

    k_detect<<<1, 64, 0, stream>>>(edge_dist, dtf);
    k_fill<<<(NNODES * 1600 + 255) / 256, 256, 0, stream>>>(accb, nden, nmax);

    k_alpha<true><<<EDGES, 256, 0, stream>>>(
        node_feats, edge_dist, wigner, emb_s, emb_r,
        rw1, rb1, rl1s, rl1b, rw2, rb2, rl2s, rl2b, rw3, rb3,
        c1w0, c1b0, an_s, an_b, adot, species, senders, receivers, dtf,
        alpha, nmax);
    k_alpha<false><<<EDGES, 256, 0, stream>>>(
        node_feats, edge_dist, wigner, emb_s, emb_r,
        rw1, rb1, rl1s, rl1b, rw2, rb2, rl2s, rl2b, rw3, rb3,
        c1w0, c1b0, an_s, an_b, adot, species, senders, receivers, dtf,
        alpha, nmax);

    k_exp<<<(EDGES * 8 + 255) / 256, 256, 0, stream>>>(receivers, nmax, alpha, nden);

    k_mega2<true><<<EDGES, 256, 0, stream>>>(
        node_feats, edge_dist, wigner, wigner_inv, to_grid, from_grid, emb_s, emb_r,
        rw1, rb1, rl1s, rl1b, rw2, rb2, rl2s, rl2b, rw3, rb3,
        c1w0, c1b0, c1w1, c1w2, c2w0, c2b0, c2w1, c2w2, proj_w,
        species, senders, receivers, dtf, alpha, nden, accb);
    k_mega2<false><<<EDGES, 256, 0, stream>>>(
        node_feats, edge_dist, wigner, wigner_inv, to_grid, from_grid, emb_s, emb_r,
        rw1, rb1, rl1s, rl1b, rw2, rb2, rl2s, rl2b, rw3, rb3,
        c1w0, c1b0, c1w1, c1w2, c2w0, c2b0, c2w1, c2w2, proj_w,
        species, senders, receivers, dtf, alpha, nden, accb);

    k_out<true><<<(NNODES * 1600 + 255) / 256, 256, 0, stream>>>(accb, proj_b, d_out, dtf);
    k_out<false><<<(NNODES * 1600 + 255) / 256, 256, 0, stream>>>(accb, proj_b, d_out, dtf);
}